// Round 9
// baseline (554.156 us; speedup 1.0000x reference)
//
#include <hip/hip_runtime.h>
#include <math.h>

#define NH   16
#define NKV  4
#define HD   128
#define BSZ  4
#define TLEN 2048
#define CDIM 2048
#define MROWS (BSZ*TLEN)   // 8192

typedef short bf16x8 __attribute__((ext_vector_type(8)));
typedef float f32x4  __attribute__((ext_vector_type(4)));
typedef int   int4v  __attribute__((ext_vector_type(4)));

__device__ inline float bf2f(unsigned short h) {
  union { unsigned u; float f; } x; x.u = ((unsigned)h) << 16; return x.f;
}
__device__ inline unsigned short f2bf(float f) {
  union { float f; unsigned u; } x; x.f = f;
  unsigned u = x.u;
  return (unsigned short)((u + 0x7FFFu + ((u >> 16) & 1u)) >> 16);
}

// Async global->LDS DMA, 16B per lane. LDS dest = wave-uniform base + lane*16.
__device__ inline void gload_lds16(const void* g, void* l) {
  __builtin_amdgcn_global_load_lds((const __attribute__((address_space(1))) void*)g,
                                   (__attribute__((address_space(3))) void*)l, 16, 0, 0);
}

// ---------------------------------------------------------------------------
// Dtype detector (unchanged): flag=1 => inputs are packed bf16.
// ---------------------------------------------------------------------------
__global__ void detect_kernel(const void* __restrict__ wproj, int* __restrict__ flag) {
  __shared__ int cnt;
  if (threadIdx.x == 0) cnt = 0;
  __syncthreads();
  const unsigned short* s = (const unsigned short*)wproj;
  unsigned short v = s[2 * threadIdx.x];          // 256 even shorts
  int e = (v >> 7) & 0xFF;
  if (e >= 90 && e <= 141) atomicAdd(&cnt, 1);
  __syncthreads();
  if (threadIdx.x == 0) *flag = (cnt >= 192) ? 1 : 0;
}

// Produce 8 contiguous bf16 from source (bf16 copy or fp32 convert).
__device__ inline void stage8(short* dst, const void* src, size_t eoff, int isbf) {
  if (isbf) {
    *(int4v*)dst = *(const int4v*)((const short*)src + eoff);
  } else {
    const f32x4* f = (const f32x4*)((const float*)src + eoff);
    f32x4 a = f[0], b = f[1];
    __align__(16) short t[8];
    t[0] = (short)f2bf(a[0]); t[1] = (short)f2bf(a[1]);
    t[2] = (short)f2bf(a[2]); t[3] = (short)f2bf(a[3]);
    t[4] = (short)f2bf(b[0]); t[5] = (short)f2bf(b[1]);
    t[6] = (short)f2bf(b[2]); t[7] = (short)f2bf(b[3]);
    *(int4v*)dst = *(int4v*)t;
  }
}

// ---------------------------------------------------------------------------
// One-shot convert/copy to packed bf16. 8 elems/thread, fully coalesced.
// ---------------------------------------------------------------------------
__global__ __launch_bounds__(256) void cvt_kernel(const void* __restrict__ src,
                                                  short* __restrict__ dst,
                                                  int n8, const int* __restrict__ flagp)
{
  const int fl = *flagp;
  const int i = blockIdx.x * 256 + threadIdx.x;
  if (i >= n8) return;
  __align__(16) short t[8];
  stage8(t, src, (size_t)i * 8, fl);
  *(int4v*)(dst + (size_t)i * 8) = *(int4v*)t;
}

// ---------------------------------------------------------------------------
// GEMM  C[m,n] = sum_k A[m,k] * W[n,k]   (bf16 inputs, fp32 accum)
// R8 structure (measured 669 TF): 256x256 tile, BK=32, 8 waves, quad-buffered
// LDS, depth-3 prefetch, counted vmcnt(8), 1 barrier/tile, setprio on MFMA.
//
// R9: MODE 0 epilogue fuses RoPE (+ q pre-scale log2e/sqrt(128) for the
// exp2-domain attn). Pair partner (d^1) lives in lane cl^1 -> __shfl_xor(.,1);
// rotation: out = fv*cos + partner*sin*sgn, sgn = (d&1) ? +1 : -1.
// Replaces the standalone rope_kernel (one kernel + 80 MB HBM round-trip).
// ---------------------------------------------------------------------------
template<int MODE>
__global__ __launch_bounds__(512, 2) void gemm_bt(
    const short* __restrict__ A, const short* __restrict__ W,
    short* __restrict__ o0, short* __restrict__ o1, short* __restrict__ o2,
    float* __restrict__ o0f, const int* __restrict__ flagp)
{
  __shared__ __align__(16) short SB[4][16384];   // 128 KB: [buf][ A:0..8191 | B:8192..16383 ]
  const int fl = *flagp;
  const int tid  = threadIdx.x;
  const int wave = tid >> 6;        // 0..7
  const int lane = tid & 63;
  const int cl   = lane & 15;
  const int quad = lane >> 4;
  const int wm = wave >> 2;         // 0..1  (M half)
  const int wn = wave & 3;          // 0..3  (N quarter)
  // bijective XCD swizzle (grids 384 / 256 blocks, both %8==0)
  const int nwgx = gridDim.x;
  int wg = (int)blockIdx.y * nwgx + (int)blockIdx.x;
  const int cpx = (nwgx * (int)gridDim.y) >> 3;
  wg = (wg & 7) * cpx + (wg >> 3);
  const int m0 = (wg / nwgx) * 256;
  const int n0 = (wg % nwgx) * 256;

  // per-thread-constant fragment read addresses (shorts):
  const int cswz  = (((cl & 1) << 2) | quad) ^ (cl >> 1);
  const int abase = (wm*64 + (cl >> 1)) * 64 + cswz * 8;           // + i*512
  const int bbase = 8192 + (wn*32 + (cl >> 1)) * 64 + cswz * 8;    // + j*512

  f32x4 acc[8][4];
#pragma unroll
  for (int i = 0; i < 8; i++)
#pragma unroll
    for (int j = 0; j < 4; j++) acc[i][j] = (f32x4){0.f, 0.f, 0.f, 0.f};

  const short* Asrc = A + (size_t)m0 * CDIM;
  const short* Wsrc = W + (size_t)n0 * CDIM;

  auto stage1 = [&](const short* src, int kk, short* dst) {
#pragma unroll
    for (int i = 0; i < 2; i++) {
      const int chunk = i*512 + tid;          // 0..1023
      const int lr  = chunk >> 3;
      const int c   = (chunk & 7) ^ (lr & 7); // inverse swizzle on SOURCE
      const int row = lr*2 + (c >> 2);
      gload_lds16(src + (size_t)row * CDIM + kk + (c & 3)*8,
                  dst + ((i*512 + wave*64) << 3));
    }
  };
#define STAGE(t) { short* db = &SB[(t)&3][0]; stage1(Asrc, (t)*32, db); stage1(Wsrc, (t)*32, db + 8192); }

  STAGE(0); STAGE(1); STAGE(2);               // 12 per-wave loads in flight
  const int nt = CDIM / 32;                   // 64 K-tiles
  for (int kt = 0; kt < nt; ++kt) {
    const int rem = nt - kt;
    if (rem > 2)       asm volatile("s_waitcnt vmcnt(8)" : : : "memory");
    else if (rem == 2) asm volatile("s_waitcnt vmcnt(4)" : : : "memory");
    else               asm volatile("s_waitcnt vmcnt(0)" : : : "memory");
    __builtin_amdgcn_s_barrier();             // all waves: tile kt landed, kt-1 reads done
    if (kt + 3 < nt) STAGE(kt+3);             // refill depth-3 pipeline
    const short* Tb = &SB[kt & 3][0];
    bf16x8 af[8], bfj[4];
#pragma unroll
    for (int i = 0; i < 8; i++) af[i]  = *(const bf16x8*)&Tb[abase + i*512];
#pragma unroll
    for (int j = 0; j < 4; j++) bfj[j] = *(const bf16x8*)&Tb[bbase + j*512];
    __builtin_amdgcn_s_setprio(1);
#pragma unroll
    for (int i = 0; i < 8; i++)
#pragma unroll
      for (int j = 0; j < 4; j++)
        acc[i][j] = __builtin_amdgcn_mfma_f32_16x16x32_bf16(af[i], bfj[j], acc[i][j], 0, 0, 0);
    __builtin_amdgcn_s_setprio(0);
  }
#undef STAGE

  // C/D layout (verified m89/m91): col = lane&15, row = quad*4 + reg.
#pragma unroll
  for (int i = 0; i < 8; i++) {
#pragma unroll
    for (int j = 0; j < 4; j++) {
      const int gn = n0 + wn*64 + j*16 + cl;
      if (MODE == 1) {
#pragma unroll
        for (int r = 0; r < 4; r++) {
          const int gm = m0 + wm*128 + i*16 + quad*4 + r;
          const float fv = acc[i][j][r];
          if (fl) o0[(size_t)gm * CDIM + gn] = (short)f2bf(fv);
          else    o0f[(size_t)gm * CDIM + gn] = fv;
        }
      } else {
        // head uniform across the wave for fixed j (16-wide window, 16-aligned)
        const int head = gn >> 7;        // 0..23
        const int d = gn & (HD - 1);
        const int dorope = (head < 20);  // q + k heads get RoPE
        const float inv = dorope ? __expf(-0.14391156847064198f * (float)(d >> 1)) : 0.f;
        const float qs  = (head < 16) ? 0.12751742f : 1.0f;   // log2e/sqrt(128) on q
        const float sgn = (d & 1) ? 1.0f : -1.0f;
#pragma unroll
        for (int r = 0; r < 4; r++) {
          const int gm = m0 + wm*128 + i*16 + quad*4 + r;
          const int b = gm >> 11;          // /TLEN
          const int t = gm & (TLEN - 1);
          float fv = acc[i][j][r];
          const float pv = __shfl_xor(fv, 1);   // RoPE pair partner (d^1)
          if (dorope) {
            float sn, cs;
            sincosf((float)t * inv, &sn, &cs);
            fv = (fv*cs + pv*sn*sgn) * qs;
          }
          const unsigned short h = f2bf(fv);
          if (head < 16) {
            o0[(((size_t)(b*NH + head) * TLEN + t) << 7) + d] = (short)h;
          } else if (head < 20) {
            o1[(((size_t)(b*NKV + (head-16)) * TLEN + t) << 7) + d] = (short)h;
          } else {
            o2[(((size_t)(b*NKV + (head-20)) * HD + d) << 11) + t] = (short)h;  // vT[b][kv][d][t]
          }
        }
      }
    }
  }
}

// ---------------------------------------------------------------------------
// Flash attention (causal), R9: exp2-domain softmax on the R7/R8 structure.
// q arrives pre-scaled by log2e/sqrt(128) (fused gemm0 epilogue), so
// P = exp2(S - m) with a single v_exp_f32 per element (no *log2e mul).
// Defer-max THR = 11.5 (== 8 nats). Everything else unchanged from R8.
// ---------------------------------------------------------------------------
__device__ inline void stage_tiles(short* Ks, short* Vs,
                                   const short* Kp, const short* Vp,
                                   int k0, int tid, int wave) {
#pragma unroll
  for (int i = 0; i < 2; i++) {
    const int chunk = i*512 + tid;
    const int row = chunk >> 4;
    const int cc  = (chunk & 15) ^ (row & 7);
    gload_lds16(Kp + (size_t)(k0 + row)*HD + cc*8,
                Ks + ((i*512 + wave*64) << 3));
  }
#pragma unroll
  for (int i = 0; i < 2; i++) {
    const int chunk = i*512 + tid;
    const int row = chunk >> 3;
    const int cc  = (chunk & 7) ^ (row & 7);
    gload_lds16(Vp + (size_t)row*TLEN + k0 + cc*8,
                Vs + ((i*512 + wave*64) << 3));
  }
}

__global__ __launch_bounds__(512, 4) void attn_kernel(
    const short* __restrict__ qb, const short* __restrict__ kb,
    const short* __restrict__ vtb, short* __restrict__ yb)
{
  __shared__ __align__(16) short Ks[2][64*128];   // 32 KB
  __shared__ __align__(16) short Vs[2][128*64];   // 32 KB
  __shared__ short Plds[8][16][64];               // 16 KB  (80 KB -> 2 blk/CU)
  const int tid  = threadIdx.x;
  const int wave = tid >> 6;       // 0..7
  const int lane = tid & 63;
  const int cl   = lane & 15;
  const int quad = lane >> 4;
  const int bh = blockIdx.y;
  const int b = bh >> 4, h = bh & 15;
  const int kvh = h >> 2;

  const short* Qp = qb  + (size_t)(b*NH  + h)   * TLEN * HD;
  const short* Kp = kb  + (size_t)(b*NKV + kvh) * TLEN * HD;
  const short* Vp = vtb + (size_t)(b*NKV + kvh) * HD * TLEN;
  short* Pw = &Plds[wave][0][0];
  const int swz = (cl & 7) << 3;   // read-side chunk XOR, in shorts

  bf16x8 ones;
#pragma unroll
  for (int i = 0; i < 8; i++) ones[i] = (short)0x3F80;  // bf16 1.0

#pragma unroll 1
  for (int pass = 0; pass < 2; ++pass) {
    const int qi = pass ? (TLEN/128 - 1 - (int)blockIdx.x) : (int)blockIdx.x;
    const int q0 = qi * 128;
    const int ntiles = 2*qi + 2;

    bf16x8 qf[4];
    const int qrow = q0 + wave*16 + cl;
#pragma unroll
    for (int s = 0; s < 4; s++)
      qf[s] = *(const bf16x8*)(Qp + (size_t)qrow*HD + s*32 + quad*8);

    f32x4 O[8];
#pragma unroll
    for (int d = 0; d < 8; d++) O[d] = (f32x4){0.f, 0.f, 0.f, 0.f};
    f32x4 Ol = (f32x4){0.f, 0.f, 0.f, 0.f};        // row sums via MFMA
    float m_i[4];
#pragma unroll
    for (int r = 0; r < 4; r++) m_i[r] = -1e9f;

    stage_tiles(Ks[0], Vs[0], Kp, Vp, 0, tid, wave);
    __syncthreads();
    int cur = 0;

    for (int kt = 0; kt < ntiles; kt++) {
      const int k0 = kt * 64;

      if (kt + 1 < ntiles)
        stage_tiles(Ks[cur^1], Vs[cur^1], Kp, Vp, k0 + 64, tid, wave);

      const short* Kt = Ks[cur];
      const short* Vt = Vs[cur];

      f32x4 S[4];
#pragma unroll
      for (int j = 0; j < 4; j++) S[j] = (f32x4){0.f, 0.f, 0.f, 0.f};
#pragma unroll
      for (int s = 0; s < 4; s++) {
        bf16x8 kfj[4];
#pragma unroll
        for (int j = 0; j < 4; j++)
          kfj[j] = *(const bf16x8*)(&Kt[(size_t)(j*16 + cl)*128 + ((((s*4 + quad) << 3) ^ swz))]);
#pragma unroll
        for (int j = 0; j < 4; j++)
          S[j] = __builtin_amdgcn_mfma_f32_16x16x32_bf16(qf[s], kfj[j], S[j], 0, 0, 0);
      }

      if (kt >= ntiles - 2) {
#pragma unroll
        for (int j = 0; j < 4; j++) {
          const int col = k0 + j*16 + cl;
#pragma unroll
          for (int r = 0; r < 4; r++) {
            const int row = q0 + wave*16 + quad*4 + r;
            if (col > row) S[j][r] = -1e9f;
          }
        }
      }

      float pmax[4];
#pragma unroll
      for (int r = 0; r < 4; r++) {
        float mx = fmaxf(fmaxf(S[0][r], S[1][r]), fmaxf(S[2][r], S[3][r]));
#pragma unroll
        for (int off = 1; off < 16; off <<= 1) mx = fmaxf(mx, __shfl_xor(mx, off));
        pmax[r] = mx;
      }
      // defer-max: THR 11.5 (log2 units) == 8 nats; P bounded by 2^11.5
      const int ok = (pmax[0] - m_i[0] <= 11.5f) && (pmax[1] - m_i[1] <= 11.5f) &&
                     (pmax[2] - m_i[2] <= 11.5f) && (pmax[3] - m_i[3] <= 11.5f);
      if (!__all(ok)) {
#pragma unroll
        for (int r = 0; r < 4; r++) {
          const float mnew = fmaxf(m_i[r], pmax[r]);
          const float alpha = exp2f(m_i[r] - mnew);
          Ol[r] *= alpha;
          m_i[r] = mnew;
#pragma unroll
          for (int d = 0; d < 8; d++) O[d][r] *= alpha;
        }
      }
#pragma unroll
      for (int r = 0; r < 4; r++)
#pragma unroll
        for (int j = 0; j < 4; j++)
          S[j][r] = exp2f(S[j][r] - m_i[r]);

#pragma unroll
      for (int j = 0; j < 4; j++)
#pragma unroll
        for (int r = 0; r < 4; r++) {
          const int row = quad*4 + r;
          int idx = row*64 + j*16 + cl;
          idx ^= (row & 7) << 3;
          Pw[idx] = (short)f2bf(S[j][r]);
        }

#pragma unroll
      for (int s2 = 0; s2 < 2; s2++) {
        int idx = cl*64 + s2*32 + quad*8;
        idx ^= (cl & 7) << 3;
        bf16x8 pf = *(const bf16x8*)(&Pw[idx]);
        Ol = __builtin_amdgcn_mfma_f32_16x16x32_bf16(pf, ones, Ol, 0, 0, 0);
#pragma unroll
        for (int d = 0; d < 8; d++) {
          bf16x8 vfd = *(const bf16x8*)(&Vt[(size_t)(d*16 + cl)*64 + ((((s2*4 + quad) << 3) ^ swz))]);
          O[d] = __builtin_amdgcn_mfma_f32_16x16x32_bf16(pf, vfd, O[d], 0, 0, 0);
        }
      }

      __syncthreads();
      cur ^= 1;
    }

    float linv[4];
#pragma unroll
    for (int r = 0; r < 4; r++) linv[r] = 1.0f / Ol[r];
#pragma unroll
    for (int d = 0; d < 8; d++) {
#pragma unroll
      for (int r = 0; r < 4; r++) {
        const int t = q0 + wave*16 + quad*4 + r;
        yb[(size_t)(b*TLEN + t) * CDIM + h*HD + d*16 + cl] = (short)f2bf(O[d][r] * linv[r]);
      }
    }
  }
}

// ---------------------------------------------------------------------------
// Memory plan (81 MB workspace peak, same as R4-R8 passing):
//   ws:   flag @ 0
//         qb  @  1MB (32MB)  q  [B,16,T,128] bf16 (RoPE'd + log2e/sqrt(128))
//         kb  @ 33MB ( 8MB)  k  [B,4,T,128]  bf16 (RoPE'd) -> wpb after attn
//         vtb @ 41MB ( 8MB)  vT [B,4,128,T]  bf16
//         yb  @ 49MB (32MB)  y  [B,T,C]      bf16
//   d_out (64MB fp32, write-only until gemm1) doubles as scratch:
//         xb  @ d_out+0    (32MB) x bf16      — dead after gemm0
//         wab @ d_out+32MB (12MB) w_attn bf16 — dead after gemm0
// ---------------------------------------------------------------------------
extern "C" void kernel_launch(void* const* d_in, const int* in_sizes, int n_in,
                              void* d_out, int out_size, void* d_ws, size_t ws_size,
                              hipStream_t stream)
{
  const void* x      = d_in[0];   // [B,T,C]
  const void* w_attn = d_in[1];   // [3072,2048]
  const void* w_proj = d_in[2];   // [2048,2048]

  char* ws = (char*)d_ws;
  int*   flag = (int*)ws;
  short* qb  = (short*)(ws + (size_t) 1*1024*1024);
  short* kb  = (short*)(ws + (size_t)33*1024*1024);
  short* vtb = (short*)(ws + (size_t)41*1024*1024);
  short* yb  = (short*)(ws + (size_t)49*1024*1024);
  short* xb  = (short*)d_out;                              // scratch in output buf
  short* wab = (short*)((char*)d_out + (size_t)32*1024*1024);
  short* wpb = kb;                                         // alias: k dead after attn

  dim3 blk(256);
  detect_kernel<<<1, blk, 0, stream>>>(w_proj, flag);
  cvt_kernel<<<dim3((MROWS*CDIM/8)/256), blk, 0, stream>>>(x, xb, MROWS*CDIM/8, flag);
  cvt_kernel<<<dim3((3072*CDIM/8)/256), blk, 0, stream>>>(w_attn, wab, 3072*CDIM/8, flag);
  gemm_bt<0><<<dim3(3072/256, MROWS/256), dim3(512), 0, stream>>>(xb, wab, qb, kb, vtb, nullptr, flag);
  attn_kernel<<<dim3(TLEN/256, BSZ*NH), dim3(512), 0, stream>>>(qb, kb, vtb, yb);
  cvt_kernel<<<dim3((CDIM*CDIM/8)/256), blk, 0, stream>>>(w_proj, wpb, CDIM*CDIM/8, flag);
  gemm_bt<1><<<dim3(CDIM/256, MROWS/256), dim3(512), 0, stream>>>(yb, wpb, (short*)d_out,
                                                                  nullptr, nullptr, (float*)d_out, flag);
}

// Round 10
// 539.937 us; speedup vs baseline: 1.0263x; 1.0263x over previous
//
#include <hip/hip_runtime.h>
#include <math.h>

#define NH   16
#define NKV  4
#define HD   128
#define BSZ  4
#define TLEN 2048
#define CDIM 2048
#define MROWS (BSZ*TLEN)   // 8192

typedef short bf16x8 __attribute__((ext_vector_type(8)));
typedef float f32x4  __attribute__((ext_vector_type(4)));
typedef int   int4v  __attribute__((ext_vector_type(4)));

__device__ inline float bf2f(unsigned short h) {
  union { unsigned u; float f; } x; x.u = ((unsigned)h) << 16; return x.f;
}
__device__ inline unsigned short f2bf(float f) {
  union { float f; unsigned u; } x; x.f = f;
  unsigned u = x.u;
  return (unsigned short)((u + 0x7FFFu + ((u >> 16) & 1u)) >> 16);
}

// Async global->LDS DMA, 16B per lane. LDS dest = wave-uniform base + lane*16.
__device__ inline void gload_lds16(const void* g, void* l) {
  __builtin_amdgcn_global_load_lds((const __attribute__((address_space(1))) void*)g,
                                   (__attribute__((address_space(3))) void*)l, 16, 0, 0);
}

// ---------------------------------------------------------------------------
// Dtype detector (unchanged): flag=1 => inputs are packed bf16.
// ---------------------------------------------------------------------------
__global__ void detect_kernel(const void* __restrict__ wproj, int* __restrict__ flag) {
  __shared__ int cnt;
  if (threadIdx.x == 0) cnt = 0;
  __syncthreads();
  const unsigned short* s = (const unsigned short*)wproj;
  unsigned short v = s[2 * threadIdx.x];          // 256 even shorts
  int e = (v >> 7) & 0xFF;
  if (e >= 90 && e <= 141) atomicAdd(&cnt, 1);
  __syncthreads();
  if (threadIdx.x == 0) *flag = (cnt >= 192) ? 1 : 0;
}

// Produce 8 contiguous bf16 from source (bf16 copy or fp32 convert).
__device__ inline void stage8(short* dst, const void* src, size_t eoff, int isbf) {
  if (isbf) {
    *(int4v*)dst = *(const int4v*)((const short*)src + eoff);
  } else {
    const f32x4* f = (const f32x4*)((const float*)src + eoff);
    f32x4 a = f[0], b = f[1];
    __align__(16) short t[8];
    t[0] = (short)f2bf(a[0]); t[1] = (short)f2bf(a[1]);
    t[2] = (short)f2bf(a[2]); t[3] = (short)f2bf(a[3]);
    t[4] = (short)f2bf(b[0]); t[5] = (short)f2bf(b[1]);
    t[6] = (short)f2bf(b[2]); t[7] = (short)f2bf(b[3]);
    *(int4v*)dst = *(int4v*)t;
  }
}

// ---------------------------------------------------------------------------
// One-shot convert/copy to packed bf16. 8 elems/thread, fully coalesced.
// ---------------------------------------------------------------------------
__global__ __launch_bounds__(256) void cvt_kernel(const void* __restrict__ src,
                                                  short* __restrict__ dst,
                                                  int n8, const int* __restrict__ flagp)
{
  const int fl = *flagp;
  const int i = blockIdx.x * 256 + threadIdx.x;
  if (i >= n8) return;
  __align__(16) short t[8];
  stage8(t, src, (size_t)i * 8, fl);
  *(int4v*)(dst + (size_t)i * 8) = *(int4v*)t;
}

// ---------------------------------------------------------------------------
// GEMM  C[m,n] = sum_k A[m,k] * W[n,k]   (bf16 inputs, fp32 accum)
// EXACT R8 structure (measured 154 us gemm0, 0 bank conflicts): 256x256 tile,
// BK=32, 8 waves (2Mx4N, 128x64 out each), quad-buffered LDS (128 KB),
// depth-3 prefetch, counted vmcnt(8) (T3+T4), 1 barrier/tile, setprio MFMA.
// R9's RoPE-in-epilogue fusion REVERTED: 21M per-element sincosf on the
// epilogue critical path cost 46 us to save rope's 16 (R9 post-mortem).
// ---------------------------------------------------------------------------
template<int MODE>
__global__ __launch_bounds__(512, 2) void gemm_bt(
    const short* __restrict__ A, const short* __restrict__ W,
    short* __restrict__ o0, short* __restrict__ o1, short* __restrict__ o2,
    float* __restrict__ o0f, const int* __restrict__ flagp)
{
  __shared__ __align__(16) short SB[4][16384];   // 128 KB: [buf][ A:0..8191 | B:8192..16383 ]
  const int fl = *flagp;
  const int tid  = threadIdx.x;
  const int wave = tid >> 6;        // 0..7
  const int lane = tid & 63;
  const int cl   = lane & 15;
  const int quad = lane >> 4;
  const int wm = wave >> 2;         // 0..1  (M half)
  const int wn = wave & 3;          // 0..3  (N quarter)
  // bijective XCD swizzle (grids 384 / 256 blocks, both %8==0)
  const int nwgx = gridDim.x;
  int wg = (int)blockIdx.y * nwgx + (int)blockIdx.x;
  const int cpx = (nwgx * (int)gridDim.y) >> 3;
  wg = (wg & 7) * cpx + (wg >> 3);
  const int m0 = (wg / nwgx) * 256;
  const int n0 = (wg % nwgx) * 256;

  // per-thread-constant fragment read addresses (shorts):
  const int cswz  = (((cl & 1) << 2) | quad) ^ (cl >> 1);
  const int abase = (wm*64 + (cl >> 1)) * 64 + cswz * 8;           // + i*512
  const int bbase = 8192 + (wn*32 + (cl >> 1)) * 64 + cswz * 8;    // + j*512

  f32x4 acc[8][4];
#pragma unroll
  for (int i = 0; i < 8; i++)
#pragma unroll
    for (int j = 0; j < 4; j++) acc[i][j] = (f32x4){0.f, 0.f, 0.f, 0.f};

  const short* Asrc = A + (size_t)m0 * CDIM;
  const short* Wsrc = W + (size_t)n0 * CDIM;

  auto stage1 = [&](const short* src, int kk, short* dst) {
#pragma unroll
    for (int i = 0; i < 2; i++) {
      const int chunk = i*512 + tid;          // 0..1023
      const int lr  = chunk >> 3;
      const int c   = (chunk & 7) ^ (lr & 7); // inverse swizzle on SOURCE
      const int row = lr*2 + (c >> 2);
      gload_lds16(src + (size_t)row * CDIM + kk + (c & 3)*8,
                  dst + ((i*512 + wave*64) << 3));
    }
  };
#define STAGE(t) { short* db = &SB[(t)&3][0]; stage1(Asrc, (t)*32, db); stage1(Wsrc, (t)*32, db + 8192); }

  STAGE(0); STAGE(1); STAGE(2);               // 12 per-wave loads in flight
  const int nt = CDIM / 32;                   // 64 K-tiles
  for (int kt = 0; kt < nt; ++kt) {
    const int rem = nt - kt;
    if (rem > 2)       asm volatile("s_waitcnt vmcnt(8)" : : : "memory");
    else if (rem == 2) asm volatile("s_waitcnt vmcnt(4)" : : : "memory");
    else               asm volatile("s_waitcnt vmcnt(0)" : : : "memory");
    __builtin_amdgcn_s_barrier();             // all waves: tile kt landed, kt-1 reads done
    if (kt + 3 < nt) STAGE(kt+3);             // refill depth-3 pipeline
    const short* Tb = &SB[kt & 3][0];
    bf16x8 af[8], bfj[4];
#pragma unroll
    for (int i = 0; i < 8; i++) af[i]  = *(const bf16x8*)&Tb[abase + i*512];
#pragma unroll
    for (int j = 0; j < 4; j++) bfj[j] = *(const bf16x8*)&Tb[bbase + j*512];
    __builtin_amdgcn_s_setprio(1);
#pragma unroll
    for (int i = 0; i < 8; i++)
#pragma unroll
      for (int j = 0; j < 4; j++)
        acc[i][j] = __builtin_amdgcn_mfma_f32_16x16x32_bf16(af[i], bfj[j], acc[i][j], 0, 0, 0);
    __builtin_amdgcn_s_setprio(0);
  }
#undef STAGE

  // C/D layout (verified m89/m91): col = lane&15, row = quad*4 + reg.
#pragma unroll
  for (int i = 0; i < 8; i++) {
#pragma unroll
    for (int j = 0; j < 4; j++) {
#pragma unroll
      for (int r = 0; r < 4; r++) {
        const int gm = m0 + wm*128 + i*16 + quad*4 + r;
        const int gn = n0 + wn*64  + j*16 + cl;
        const float fv = acc[i][j][r];
        if (MODE == 1) {
          if (fl) o0[(size_t)gm * CDIM + gn] = (short)f2bf(fv);
          else    o0f[(size_t)gm * CDIM + gn] = fv;
        } else {
          const int b = gm >> 11;          // /TLEN
          const int t = gm & (TLEN - 1);
          const int head = gn >> 7;        // 0..23
          const int d = gn & (HD - 1);
          const unsigned short h = f2bf(fv);
          if (head < 16) {
            o0[(((size_t)(b*NH + head) * TLEN + t) << 7) + d] = (short)h;
          } else if (head < 20) {
            o1[(((size_t)(b*NKV + (head-16)) * TLEN + t) << 7) + d] = (short)h;
          } else {
            o2[(((size_t)(b*NKV + (head-20)) * HD + d) << 11) + t] = (short)h;  // vT[b][kv][d][t]
          }
        }
      }
    }
  }
}

// ---------------------------------------------------------------------------
// RoPE in place (standalone again — R9 fusion reverted). q planes get
// log2e/sqrt(128) folded in for the exp2-domain attn softmax.
// ---------------------------------------------------------------------------
__global__ __launch_bounds__(256) void rope_kernel(short* __restrict__ qb,
                                                   short* __restrict__ kb)
{
  const int idx = blockIdx.x * 256 + threadIdx.x;   // exactly 80*2048*64 threads
  const int per_plane = TLEN * 64;
  const int plane = idx / per_plane;
  const int rem = idx - plane * per_plane;
  const int t = rem >> 6;
  const int i = rem & 63;
  short* base = (plane < 64) ? (qb + (size_t)plane * (TLEN*HD))
                             : (kb + (size_t)(plane - 64) * (TLEN*HD));
  const size_t off = (size_t)t * HD + 2*i;
  const float x1 = bf2f((unsigned short)base[off]);
  const float x2 = bf2f((unsigned short)base[off+1]);
  const float inv = __expf(-0.14391156847064198f * (float)i);  // 10000^(-2i/128)
  const float ang = (float)t * inv;
  float s, c;
  sincosf(ang, &s, &c);
  const float qscale = (plane < 64) ? 0.12751742f : 1.0f;  // log2e/sqrt(128) on q
  base[off]   = (short)f2bf((x1*c - x2*s) * qscale);
  base[off+1] = (short)f2bf((x1*s + x2*c) * qscale);
}

// ---------------------------------------------------------------------------
// Flash attention (causal) — R9 exp2-domain version (kept): q pre-scaled by
// log2e/sqrt(128), P = exp2(S-m), defer-max THR 11.5 (= 8 nats). Structure:
// 8 waves, MFMA row-sum, coop double-buffered gload_lds staging (R7/R8).
// ---------------------------------------------------------------------------
__device__ inline void stage_tiles(short* Ks, short* Vs,
                                   const short* Kp, const short* Vp,
                                   int k0, int tid, int wave) {
#pragma unroll
  for (int i = 0; i < 2; i++) {
    const int chunk = i*512 + tid;
    const int row = chunk >> 4;
    const int cc  = (chunk & 15) ^ (row & 7);
    gload_lds16(Kp + (size_t)(k0 + row)*HD + cc*8,
                Ks + ((i*512 + wave*64) << 3));
  }
#pragma unroll
  for (int i = 0; i < 2; i++) {
    const int chunk = i*512 + tid;
    const int row = chunk >> 3;
    const int cc  = (chunk & 7) ^ (row & 7);
    gload_lds16(Vp + (size_t)row*TLEN + k0 + cc*8,
                Vs + ((i*512 + wave*64) << 3));
  }
}

__global__ __launch_bounds__(512, 4) void attn_kernel(
    const short* __restrict__ qb, const short* __restrict__ kb,
    const short* __restrict__ vtb, short* __restrict__ yb)
{
  __shared__ __align__(16) short Ks[2][64*128];   // 32 KB
  __shared__ __align__(16) short Vs[2][128*64];   // 32 KB
  __shared__ short Plds[8][16][64];               // 16 KB  (80 KB -> 2 blk/CU)
  const int tid  = threadIdx.x;
  const int wave = tid >> 6;       // 0..7
  const int lane = tid & 63;
  const int cl   = lane & 15;
  const int quad = lane >> 4;
  const int bh = blockIdx.y;
  const int b = bh >> 4, h = bh & 15;
  const int kvh = h >> 2;

  const short* Qp = qb  + (size_t)(b*NH  + h)   * TLEN * HD;
  const short* Kp = kb  + (size_t)(b*NKV + kvh) * TLEN * HD;
  const short* Vp = vtb + (size_t)(b*NKV + kvh) * HD * TLEN;
  short* Pw = &Plds[wave][0][0];
  const int swz = (cl & 7) << 3;   // read-side chunk XOR, in shorts

  bf16x8 ones;
#pragma unroll
  for (int i = 0; i < 8; i++) ones[i] = (short)0x3F80;  // bf16 1.0

#pragma unroll 1
  for (int pass = 0; pass < 2; ++pass) {
    const int qi = pass ? (TLEN/128 - 1 - (int)blockIdx.x) : (int)blockIdx.x;
    const int q0 = qi * 128;
    const int ntiles = 2*qi + 2;

    bf16x8 qf[4];
    const int qrow = q0 + wave*16 + cl;
#pragma unroll
    for (int s = 0; s < 4; s++)
      qf[s] = *(const bf16x8*)(Qp + (size_t)qrow*HD + s*32 + quad*8);

    f32x4 O[8];
#pragma unroll
    for (int d = 0; d < 8; d++) O[d] = (f32x4){0.f, 0.f, 0.f, 0.f};
    f32x4 Ol = (f32x4){0.f, 0.f, 0.f, 0.f};        // row sums via MFMA
    float m_i[4];
#pragma unroll
    for (int r = 0; r < 4; r++) m_i[r] = -1e9f;

    stage_tiles(Ks[0], Vs[0], Kp, Vp, 0, tid, wave);
    __syncthreads();
    int cur = 0;

    for (int kt = 0; kt < ntiles; kt++) {
      const int k0 = kt * 64;

      if (kt + 1 < ntiles)
        stage_tiles(Ks[cur^1], Vs[cur^1], Kp, Vp, k0 + 64, tid, wave);

      const short* Kt = Ks[cur];
      const short* Vt = Vs[cur];

      f32x4 S[4];
#pragma unroll
      for (int j = 0; j < 4; j++) S[j] = (f32x4){0.f, 0.f, 0.f, 0.f};
#pragma unroll
      for (int s = 0; s < 4; s++) {
        bf16x8 kfj[4];
#pragma unroll
        for (int j = 0; j < 4; j++)
          kfj[j] = *(const bf16x8*)(&Kt[(size_t)(j*16 + cl)*128 + ((((s*4 + quad) << 3) ^ swz))]);
#pragma unroll
        for (int j = 0; j < 4; j++)
          S[j] = __builtin_amdgcn_mfma_f32_16x16x32_bf16(qf[s], kfj[j], S[j], 0, 0, 0);
      }

      if (kt >= ntiles - 2) {
#pragma unroll
        for (int j = 0; j < 4; j++) {
          const int col = k0 + j*16 + cl;
#pragma unroll
          for (int r = 0; r < 4; r++) {
            const int row = q0 + wave*16 + quad*4 + r;
            if (col > row) S[j][r] = -1e9f;
          }
        }
      }

      float pmax[4];
#pragma unroll
      for (int r = 0; r < 4; r++) {
        float mx = fmaxf(fmaxf(S[0][r], S[1][r]), fmaxf(S[2][r], S[3][r]));
#pragma unroll
        for (int off = 1; off < 16; off <<= 1) mx = fmaxf(mx, __shfl_xor(mx, off));
        pmax[r] = mx;
      }
      // defer-max: THR 11.5 (log2 units) == 8 nats; P bounded by 2^11.5
      const int ok = (pmax[0] - m_i[0] <= 11.5f) && (pmax[1] - m_i[1] <= 11.5f) &&
                     (pmax[2] - m_i[2] <= 11.5f) && (pmax[3] - m_i[3] <= 11.5f);
      if (!__all(ok)) {
#pragma unroll
        for (int r = 0; r < 4; r++) {
          const float mnew = fmaxf(m_i[r], pmax[r]);
          const float alpha = exp2f(m_i[r] - mnew);
          Ol[r] *= alpha;
          m_i[r] = mnew;
#pragma unroll
          for (int d = 0; d < 8; d++) O[d][r] *= alpha;
        }
      }
#pragma unroll
      for (int r = 0; r < 4; r++)
#pragma unroll
        for (int j = 0; j < 4; j++)
          S[j][r] = exp2f(S[j][r] - m_i[r]);

#pragma unroll
      for (int j = 0; j < 4; j++)
#pragma unroll
        for (int r = 0; r < 4; r++) {
          const int row = quad*4 + r;
          int idx = row*64 + j*16 + cl;
          idx ^= (row & 7) << 3;
          Pw[idx] = (short)f2bf(S[j][r]);
        }

#pragma unroll
      for (int s2 = 0; s2 < 2; s2++) {
        int idx = cl*64 + s2*32 + quad*8;
        idx ^= (cl & 7) << 3;
        bf16x8 pf = *(const bf16x8*)(&Pw[idx]);
        Ol = __builtin_amdgcn_mfma_f32_16x16x32_bf16(pf, ones, Ol, 0, 0, 0);
#pragma unroll
        for (int d = 0; d < 8; d++) {
          bf16x8 vfd = *(const bf16x8*)(&Vt[(size_t)(d*16 + cl)*64 + ((((s2*4 + quad) << 3) ^ swz))]);
          O[d] = __builtin_amdgcn_mfma_f32_16x16x32_bf16(pf, vfd, O[d], 0, 0, 0);
        }
      }

      __syncthreads();
      cur ^= 1;
    }

    float linv[4];
#pragma unroll
    for (int r = 0; r < 4; r++) linv[r] = 1.0f / Ol[r];
#pragma unroll
    for (int d = 0; d < 8; d++) {
#pragma unroll
      for (int r = 0; r < 4; r++) {
        const int t = q0 + wave*16 + quad*4 + r;
        yb[(size_t)(b*TLEN + t) * CDIM + h*HD + d*16 + cl] = (short)f2bf(O[d][r] * linv[r]);
      }
    }
  }
}

// ---------------------------------------------------------------------------
// Memory plan (81 MB workspace peak, same as R4-R8 passing):
//   ws:   flag @ 0
//         qb  @  1MB (32MB)  q  [B,16,T,128] bf16 (RoPE'd + log2e/sqrt(128))
//         kb  @ 33MB ( 8MB)  k  [B,4,T,128]  bf16 (RoPE'd) -> wpb after attn
//         vtb @ 41MB ( 8MB)  vT [B,4,128,T]  bf16
//         yb  @ 49MB (32MB)  y  [B,T,C]      bf16
//   d_out (64MB fp32, write-only until gemm1) doubles as scratch:
//         xb  @ d_out+0    (32MB) x bf16      — dead after gemm0
//         wab @ d_out+32MB (12MB) w_attn bf16 — dead after gemm0
// ---------------------------------------------------------------------------
extern "C" void kernel_launch(void* const* d_in, const int* in_sizes, int n_in,
                              void* d_out, int out_size, void* d_ws, size_t ws_size,
                              hipStream_t stream)
{
  const void* x      = d_in[0];   // [B,T,C]
  const void* w_attn = d_in[1];   // [3072,2048]
  const void* w_proj = d_in[2];   // [2048,2048]

  char* ws = (char*)d_ws;
  int*   flag = (int*)ws;
  short* qb  = (short*)(ws + (size_t) 1*1024*1024);
  short* kb  = (short*)(ws + (size_t)33*1024*1024);
  short* vtb = (short*)(ws + (size_t)41*1024*1024);
  short* yb  = (short*)(ws + (size_t)49*1024*1024);
  short* xb  = (short*)d_out;                              // scratch in output buf
  short* wab = (short*)((char*)d_out + (size_t)32*1024*1024);
  short* wpb = kb;                                         // alias: k dead after attn

  dim3 blk(256);
  detect_kernel<<<1, blk, 0, stream>>>(w_proj, flag);
  cvt_kernel<<<dim3((MROWS*CDIM/8)/256), blk, 0, stream>>>(x, xb, MROWS*CDIM/8, flag);
  cvt_kernel<<<dim3((3072*CDIM/8)/256), blk, 0, stream>>>(w_attn, wab, 3072*CDIM/8, flag);
  gemm_bt<0><<<dim3(3072/256, MROWS/256), dim3(512), 0, stream>>>(xb, wab, qb, kb, vtb, nullptr, flag);
  rope_kernel<<<dim3((80*TLEN*64)/256), blk, 0, stream>>>(qb, kb);
  attn_kernel<<<dim3(TLEN/256, BSZ*NH), dim3(512), 0, stream>>>(qb, kb, vtb, yb);
  cvt_kernel<<<dim3((CDIM*CDIM/8)/256), blk, 0, stream>>>(w_proj, wpb, CDIM*CDIM/8, flag);
  gemm_bt<1><<<dim3(CDIM/256, MROWS/256), dim3(512), 0, stream>>>(yb, wpb, (short*)d_out,
                                                                  nullptr, nullptr, (float*)d_out, flag);
}